// Round 5
// baseline (177.581 us; speedup 1.0000x reference)
//
#include <hip/hip_runtime.h>

#define DEV __device__ __forceinline__

// Hardware wait for all outstanding LDS ops + compiler reorder fence.
#define LDS_FENCE() asm volatile("s_waitcnt lgkmcnt(0)" ::: "memory")

DEV float4 fma4(float4 acc, float s, float4 v) {
    acc.x = fmaf(s, v.x, acc.x);
    acc.y = fmaf(s, v.y, acc.y);
    acc.z = fmaf(s, v.z, acc.z);
    acc.w = fmaf(s, v.w, acc.w);
    return acc;
}

DEV float fast_sigmoid(float v) {
    // sigmoid(v) = 1 / (1 + 2^(-v*log2e))
    return __builtin_amdgcn_rcpf(1.0f + __builtin_amdgcn_exp2f(-1.4426950408889634f * v));
}

// Per-sample math: p[51] joints, a[17] anchors, g[16] gt bone lengths,
// weights in LDS. Produces o[51]. All arrays statically indexed (stay in VGPRs).
DEV void compute_sample(const float (&p)[51], const float (&a)[17], const float (&g)[16],
                        const float* sW1, const float* sW2, float (&o)[51])
{
    constexpr int PAR[16] = {0,1,2,0,4,5,0,7,8,9,8,11,12,8,14,15};
    constexpr int CHI[16] = {1,2,3,4,5,6,7,8,9,10,11,12,13,14,15,16};

    float x[32], invn[16];
    #pragma unroll
    for (int k = 0; k < 16; ++k) {
        const int P = PAR[k] * 3, C = CHI[k] * 3;
        const float dx = p[P]   - p[C];
        const float dy = p[P+1] - p[C+1];
        const float dz = p[P+2] - p[C+2];
        const float n  = __builtin_amdgcn_sqrtf(fmaf(dx,dx, fmaf(dy,dy, dz*dz)));
        const float dis = g[k] - n;
        const float ap = a[PAR[k]], ac = a[CHI[k]];
        const float inv_asum = __builtin_amdgcn_rcpf(ap + ac + 1e-9f);
        x[2*k]   = dis * ac * inv_asum;
        x[2*k+1] = dis * ap * inv_asum;
        invn[k]  = __builtin_amdgcn_rcpf(n + 1e-9f);
    }

    const float4* w1v = reinterpret_cast<const float4*>(sW1);
    const float4* w2v = reinterpret_cast<const float4*>(sW2);

    float4 y0 = {0,0,0,0}, y1 = {0,0,0,0}, y2 = {0,0,0,0}, y3 = {0,0,0,0};
    #pragma unroll
    for (int i = 0; i < 32; ++i) {
        const float xi = x[i];
        y0 = fma4(y0, xi, w1v[i*4+0]);
        y1 = fma4(y1, xi, w1v[i*4+1]);
        y2 = fma4(y2, xi, w1v[i*4+2]);
        y3 = fma4(y3, xi, w1v[i*4+3]);
    }
    float h[16];
    h[0]=fmaxf(y0.x,0.f);  h[1]=fmaxf(y0.y,0.f);  h[2]=fmaxf(y0.z,0.f);  h[3]=fmaxf(y0.w,0.f);
    h[4]=fmaxf(y1.x,0.f);  h[5]=fmaxf(y1.y,0.f);  h[6]=fmaxf(y1.z,0.f);  h[7]=fmaxf(y1.w,0.f);
    h[8]=fmaxf(y2.x,0.f);  h[9]=fmaxf(y2.y,0.f);  h[10]=fmaxf(y2.z,0.f); h[11]=fmaxf(y2.w,0.f);
    h[12]=fmaxf(y3.x,0.f); h[13]=fmaxf(y3.y,0.f); h[14]=fmaxf(y3.z,0.f); h[15]=fmaxf(y3.w,0.f);

    float xg[32];
    #pragma unroll
    for (int c = 0; c < 8; ++c) {
        float4 gq = {0,0,0,0};
        #pragma unroll
        for (int j = 0; j < 16; ++j) gq = fma4(gq, h[j], w2v[j*8 + c]);
        xg[4*c+0] = x[4*c+0] * fast_sigmoid(gq.x);
        xg[4*c+1] = x[4*c+1] * fast_sigmoid(gq.y);
        xg[4*c+2] = x[4*c+2] * fast_sigmoid(gq.z);
        xg[4*c+3] = x[4*c+3] * fast_sigmoid(gq.w);
    }
    #pragma unroll
    for (int k = 0; k < 16; ++k) {
        xg[2*k]   *= invn[k];
        xg[2*k+1] *= invn[k];
    }

    #pragma unroll
    for (int j = 0; j < 17; ++j) {
        float ox = p[3*j], oy = p[3*j+1], oz = p[3*j+2];
        #pragma unroll
        for (int k = 0; k < 16; ++k) {
            if (PAR[k] == j || CHI[k] == j) {   // compile-time after unroll
                const int P = PAR[k] * 3, C = CHI[k] * 3;
                const float dx = p[P]   - p[C];
                const float dy = p[P+1] - p[C+1];
                const float dz = p[P+2] - p[C+2];
                const float s = (PAR[k] == j) ? xg[2*k] : -xg[2*k+1];
                ox = fmaf(s, dx, ox);
                oy = fmaf(s, dy, oy);
                oz = fmaf(s, dz, oz);
            }
        }
        o[3*j]   = ox;
        o[3*j+1] = oy;
        o[3*j+2] = oz;
    }
}

__global__ __launch_bounds__(256) void projts_kernel(
    const float* __restrict__ pred,
    const float* __restrict__ gt,
    const float* __restrict__ anc,
    const float* __restrict__ gW1,
    const float* __restrict__ gW2,
    float* __restrict__ out,
    int B)
{
    constexpr int ROW = 51;            // floats per sample in pred/out
    constexpr int WBUF = 64 * ROW;     // 3264 dwords = 13056 B per wave
    constexpr int ABUF = 64 * 17;      // 1088 dwords = 4352 B per wave

    __shared__ float sW1[512]  __attribute__((aligned(16)));  // [32][16]
    __shared__ float sW2[512]  __attribute__((aligned(16)));  // [16][32]
    __shared__ float sbuf[4][WBUF] __attribute__((aligned(16)));  // pred/out
    __shared__ float abuf[4][ABUF] __attribute__((aligned(16)));  // anchors

    const int t = threadIdx.x;
    {
        float4* s1 = reinterpret_cast<float4*>(sW1);
        float4* s2 = reinterpret_cast<float4*>(sW2);
        const float4* g1 = reinterpret_cast<const float4*>(gW1);
        const float4* g2 = reinterpret_cast<const float4*>(gW2);
        if (t < 128)      s1[t] = g1[t];
        else if (t < 256) s2[t - 128] = g2[t - 128];
    }
    __syncthreads();

    const int w = t >> 6;
    const int l = t & 63;
    const long long wavebase = ((long long)blockIdx.x * 4 + w) * 64;
    if (wavebase >= B) return;

    float* buf  = sbuf[w];
    float4* buf4 = reinterpret_cast<float4*>(buf);
    float* abf  = abuf[w];
    float4* abf4 = reinterpret_cast<float4*>(abf);

    if (wavebase + 64 <= (long long)B) {
        // ================= coalesced fast path (full wave) =================
        float p[51], a[17], o[51];

        // ---- issue ALL global loads up front (one HBM round-trip) ----
        const float4* src4  = reinterpret_cast<const float4*>(pred + (size_t)wavebase * ROW);
        const float4* asrc4 = reinterpret_cast<const float4*>(anc + (size_t)wavebase * 17);
        const float4* gsrc4 = reinterpret_cast<const float4*>(gt + (size_t)(wavebase + l) * 16);

        float4 pr[13];
        #pragma unroll
        for (int i = 0; i < 12; ++i) pr[i] = src4[i*64 + l];
        if (l < 48) pr[12] = src4[768 + l];

        float4 ar[5];
        #pragma unroll
        for (int i = 0; i < 4; ++i) ar[i] = asrc4[i*64 + l];
        if (l < 16) ar[4] = asrc4[256 + l];

        const float4 gq0 = gsrc4[0], gq1 = gsrc4[1], gq2 = gsrc4[2], gq3 = gsrc4[3];

        // ---- write staging (compiler inserts counted vmcnt per value) ----
        #pragma unroll
        for (int i = 0; i < 12; ++i) buf4[i*64 + l] = pr[i];
        if (l < 48) buf4[768 + l] = pr[12];
        #pragma unroll
        for (int i = 0; i < 4; ++i) abf4[i*64 + l] = ar[i];
        if (l < 16) abf4[256 + l] = ar[4];
        LDS_FENCE();   // all staging writes visible

        // ---- transposed readback: strides 51 / 17 (odd) -> conflict-free ----
        #pragma unroll
        for (int j = 0; j < ROW; ++j) p[j] = buf[l*ROW + j];
        #pragma unroll
        for (int j = 0; j < 17; ++j) a[j] = abf[l*17 + j];
        LDS_FENCE();   // p-reads done before out overwrites pred region (WAR)

        const float g[16] = {gq0.x,gq0.y,gq0.z,gq0.w, gq1.x,gq1.y,gq1.z,gq1.w,
                             gq2.x,gq2.y,gq2.z,gq2.w, gq3.x,gq3.y,gq3.z,gq3.w};

        compute_sample(p, a, g, sW1, sW2, o);

        // ---- transpose out through LDS (reuse pred region), coalesced stores ----
        #pragma unroll
        for (int j = 0; j < ROW; ++j) buf[l*ROW + j] = o[j];
        LDS_FENCE();

        float4* dst4 = reinterpret_cast<float4*>(out + (size_t)wavebase * ROW);
        #pragma unroll
        for (int i = 0; i < 12; ++i) dst4[i*64 + l] = buf4[i*64 + l];
        if (l < 48) dst4[768 + l] = buf4[768 + l];
    } else {
        // ================= scalar tail path (partial wave) =================
        const long long b = wavebase + l;
        if (b < B) {
            float p[51], a[17], g[16], o[51];
            const float* pj = pred + (size_t)b * 51;
            #pragma unroll
            for (int j = 0; j < 51; ++j) p[j] = pj[j];
            const float* ab = anc + (size_t)b * 17;
            #pragma unroll
            for (int j = 0; j < 17; ++j) a[j] = ab[j];
            const float* gb = gt + (size_t)b * 16;
            #pragma unroll
            for (int j = 0; j < 16; ++j) g[j] = gb[j];

            compute_sample(p, a, g, sW1, sW2, o);

            float* ob = out + (size_t)b * 51;
            #pragma unroll
            for (int j = 0; j < 51; ++j) ob[j] = o[j];
        }
    }
}

extern "C" void kernel_launch(void* const* d_in, const int* in_sizes, int n_in,
                              void* d_out, int out_size, void* d_ws, size_t ws_size,
                              hipStream_t stream) {
    const float* pred = (const float*)d_in[0];
    const float* gt   = (const float*)d_in[1];
    const float* anc  = (const float*)d_in[2];
    const float* W1   = (const float*)d_in[3];
    const float* W2   = (const float*)d_in[4];
    float* out = (float*)d_out;

    const int B = in_sizes[0] / 51;
    const int blocks = (B + 255) / 256;
    hipLaunchKernelGGL(projts_kernel, dim3(blocks), dim3(256), 0, stream,
                       pred, gt, anc, W1, W2, out, B);
}

// Round 6
// 109.500 us; speedup vs baseline: 1.6217x; 1.6217x over previous
//
#include <hip/hip_runtime.h>

#define DEV __device__ __forceinline__

// Hardware waits + compiler reorder fences.
#define LDS_FENCE() asm volatile("s_waitcnt lgkmcnt(0)" ::: "memory")
#define VM_FENCE()  asm volatile("s_waitcnt vmcnt(0)" ::: "memory")

// Direct global->LDS DMA, 16B per lane. LDS dest = uniform base + lane*16,
// global src = per-lane address. (cdna_hip_programming.md §5, m97/m104.)
DEV void gload_lds16(const void* g, void* lds) {
    __builtin_amdgcn_global_load_lds(
        (const __attribute__((address_space(1))) void*)g,
        (__attribute__((address_space(3))) void*)lds,
        16, 0, 0);
}

DEV float4 fma4(float4 acc, float s, float4 v) {
    acc.x = fmaf(s, v.x, acc.x);
    acc.y = fmaf(s, v.y, acc.y);
    acc.z = fmaf(s, v.z, acc.z);
    acc.w = fmaf(s, v.w, acc.w);
    return acc;
}

DEV float fast_sigmoid(float v) {
    return __builtin_amdgcn_rcpf(1.0f + __builtin_amdgcn_exp2f(-1.4426950408889634f * v));
}

// Per-sample math: all arrays statically indexed (stay in VGPRs).
DEV void compute_sample(const float (&p)[51], const float (&a)[17], const float (&g)[16],
                        const float* sW1, const float* sW2, float (&o)[51])
{
    constexpr int PAR[16] = {0,1,2,0,4,5,0,7,8,9,8,11,12,8,14,15};
    constexpr int CHI[16] = {1,2,3,4,5,6,7,8,9,10,11,12,13,14,15,16};

    float x[32], invn[16];
    #pragma unroll
    for (int k = 0; k < 16; ++k) {
        const int P = PAR[k] * 3, C = CHI[k] * 3;
        const float dx = p[P]   - p[C];
        const float dy = p[P+1] - p[C+1];
        const float dz = p[P+2] - p[C+2];
        const float n  = __builtin_amdgcn_sqrtf(fmaf(dx,dx, fmaf(dy,dy, dz*dz)));
        const float dis = g[k] - n;
        const float ap = a[PAR[k]], ac = a[CHI[k]];
        const float inv_asum = __builtin_amdgcn_rcpf(ap + ac + 1e-9f);
        x[2*k]   = dis * ac * inv_asum;
        x[2*k+1] = dis * ap * inv_asum;
        invn[k]  = __builtin_amdgcn_rcpf(n + 1e-9f);
    }

    const float4* w1v = reinterpret_cast<const float4*>(sW1);
    const float4* w2v = reinterpret_cast<const float4*>(sW2);

    float4 y0 = {0,0,0,0}, y1 = {0,0,0,0}, y2 = {0,0,0,0}, y3 = {0,0,0,0};
    #pragma unroll
    for (int i = 0; i < 32; ++i) {
        const float xi = x[i];
        y0 = fma4(y0, xi, w1v[i*4+0]);
        y1 = fma4(y1, xi, w1v[i*4+1]);
        y2 = fma4(y2, xi, w1v[i*4+2]);
        y3 = fma4(y3, xi, w1v[i*4+3]);
    }
    float h[16];
    h[0]=fmaxf(y0.x,0.f);  h[1]=fmaxf(y0.y,0.f);  h[2]=fmaxf(y0.z,0.f);  h[3]=fmaxf(y0.w,0.f);
    h[4]=fmaxf(y1.x,0.f);  h[5]=fmaxf(y1.y,0.f);  h[6]=fmaxf(y1.z,0.f);  h[7]=fmaxf(y1.w,0.f);
    h[8]=fmaxf(y2.x,0.f);  h[9]=fmaxf(y2.y,0.f);  h[10]=fmaxf(y2.z,0.f); h[11]=fmaxf(y2.w,0.f);
    h[12]=fmaxf(y3.x,0.f); h[13]=fmaxf(y3.y,0.f); h[14]=fmaxf(y3.z,0.f); h[15]=fmaxf(y3.w,0.f);

    float xg[32];
    #pragma unroll
    for (int c = 0; c < 8; ++c) {
        float4 gq = {0,0,0,0};
        #pragma unroll
        for (int j = 0; j < 16; ++j) gq = fma4(gq, h[j], w2v[j*8 + c]);
        xg[4*c+0] = x[4*c+0] * fast_sigmoid(gq.x);
        xg[4*c+1] = x[4*c+1] * fast_sigmoid(gq.y);
        xg[4*c+2] = x[4*c+2] * fast_sigmoid(gq.z);
        xg[4*c+3] = x[4*c+3] * fast_sigmoid(gq.w);
    }
    #pragma unroll
    for (int k = 0; k < 16; ++k) {
        xg[2*k]   *= invn[k];
        xg[2*k+1] *= invn[k];
    }

    #pragma unroll
    for (int j = 0; j < 17; ++j) {
        float ox = p[3*j], oy = p[3*j+1], oz = p[3*j+2];
        #pragma unroll
        for (int k = 0; k < 16; ++k) {
            if (PAR[k] == j || CHI[k] == j) {   // compile-time after unroll
                const int P = PAR[k] * 3, C = CHI[k] * 3;
                const float dx = p[P]   - p[C];
                const float dy = p[P+1] - p[C+1];
                const float dz = p[P+2] - p[C+2];
                const float s = (PAR[k] == j) ? xg[2*k] : -xg[2*k+1];
                ox = fmaf(s, dx, ox);
                oy = fmaf(s, dy, oy);
                oz = fmaf(s, dz, oz);
            }
        }
        o[3*j]   = ox;
        o[3*j+1] = oy;
        o[3*j+2] = oz;
    }
}

__global__ __launch_bounds__(256, 2) void projts_kernel(
    const float* __restrict__ pred,
    const float* __restrict__ gt,
    const float* __restrict__ anc,
    const float* __restrict__ gW1,
    const float* __restrict__ gW2,
    float* __restrict__ out,
    int B)
{
    constexpr int ROW = 51;            // floats per sample in pred/out
    constexpr int WBUF = 64 * ROW;     // 3264 dwords = 13056 B per wave
    constexpr int ABUF = 64 * 17;      // 1088 dwords = 4352 B per wave

    __shared__ float sW1[512]  __attribute__((aligned(16)));  // [32][16]
    __shared__ float sW2[512]  __attribute__((aligned(16)));  // [16][32]
    __shared__ float sbuf[4][WBUF] __attribute__((aligned(16)));  // pred/out
    __shared__ float abuf[4][ABUF] __attribute__((aligned(16)));  // anchors

    const int t = threadIdx.x;
    {
        float4* s1 = reinterpret_cast<float4*>(sW1);
        float4* s2 = reinterpret_cast<float4*>(sW2);
        const float4* g1 = reinterpret_cast<const float4*>(gW1);
        const float4* g2 = reinterpret_cast<const float4*>(gW2);
        if (t < 128)      s1[t] = g1[t];
        else if (t < 256) s2[t - 128] = g2[t - 128];
    }
    __syncthreads();

    const int w = t >> 6;
    const int l = t & 63;
    const long long wavebase = ((long long)blockIdx.x * 4 + w) * 64;
    if (wavebase >= B) return;

    float* buf  = sbuf[w];
    float4* buf4 = reinterpret_cast<float4*>(buf);
    float* abf  = abuf[w];

    if (wavebase + 64 <= (long long)B) {
        // ================= coalesced fast path (full wave) =================
        float p[51], a[17], o[51];

        const char* srcB = reinterpret_cast<const char*>(pred + (size_t)wavebase * ROW);
        const char* ascB = reinterpret_cast<const char*>(anc + (size_t)wavebase * 17);
        char* bufB = reinterpret_cast<char*>(buf);
        char* abfB = reinterpret_cast<char*>(abf);

        // ---- pred: 816 float4 via global_load_lds (13 issues, last masked) ----
        #pragma unroll
        for (int i = 0; i < 12; ++i)
            gload_lds16(srcB + (size_t)(i*64 + l)*16, bufB + i*1024);
        if (l < 48)
            gload_lds16(srcB + (size_t)(768 + l)*16, bufB + 12*1024);

        // ---- anchors: 272 float4 via global_load_lds (5 issues, last masked) ----
        #pragma unroll
        for (int i = 0; i < 4; ++i)
            gload_lds16(ascB + (size_t)(i*64 + l)*16, abfB + i*1024);
        if (l < 16)
            gload_lds16(ascB + (size_t)(256 + l)*16, abfB + 4*1024);

        // ---- gt: 64B/sample, 16B aligned -> direct float4 reg loads ----
        const float4* gsrc4 = reinterpret_cast<const float4*>(gt + (size_t)(wavebase + l) * 16);
        const float4 gq0 = gsrc4[0], gq1 = gsrc4[1], gq2 = gsrc4[2], gq3 = gsrc4[3];

        VM_FENCE();    // all global_load_lds (and gt loads) complete

        // ---- transposed readback: strides 51 / 17 (odd) -> conflict-free ----
        #pragma unroll
        for (int j = 0; j < ROW; ++j) p[j] = buf[l*ROW + j];
        #pragma unroll
        for (int j = 0; j < 17; ++j) a[j] = abf[l*17 + j];
        LDS_FENCE();   // reads drained before out overwrites pred region (WAR)

        const float g[16] = {gq0.x,gq0.y,gq0.z,gq0.w, gq1.x,gq1.y,gq1.z,gq1.w,
                             gq2.x,gq2.y,gq2.z,gq2.w, gq3.x,gq3.y,gq3.z,gq3.w};

        compute_sample(p, a, g, sW1, sW2, o);

        // ---- transpose out through LDS (reuse pred region), coalesced stores ----
        #pragma unroll
        for (int j = 0; j < ROW; ++j) buf[l*ROW + j] = o[j];
        LDS_FENCE();

        float4* dst4 = reinterpret_cast<float4*>(out + (size_t)wavebase * ROW);
        #pragma unroll
        for (int i = 0; i < 12; ++i) dst4[i*64 + l] = buf4[i*64 + l];
        if (l < 48) dst4[768 + l] = buf4[768 + l];
    } else {
        // ================= scalar tail path (partial wave) =================
        const long long b = wavebase + l;
        if (b < B) {
            float p[51], a[17], g[16], o[51];
            const float* pj = pred + (size_t)b * 51;
            #pragma unroll
            for (int j = 0; j < 51; ++j) p[j] = pj[j];
            const float* ab = anc + (size_t)b * 17;
            #pragma unroll
            for (int j = 0; j < 17; ++j) a[j] = ab[j];
            const float* gb = gt + (size_t)b * 16;
            #pragma unroll
            for (int j = 0; j < 16; ++j) g[j] = gb[j];

            compute_sample(p, a, g, sW1, sW2, o);

            float* ob = out + (size_t)b * 51;
            #pragma unroll
            for (int j = 0; j < 51; ++j) ob[j] = o[j];
        }
    }
}

extern "C" void kernel_launch(void* const* d_in, const int* in_sizes, int n_in,
                              void* d_out, int out_size, void* d_ws, size_t ws_size,
                              hipStream_t stream) {
    const float* pred = (const float*)d_in[0];
    const float* gt   = (const float*)d_in[1];
    const float* anc  = (const float*)d_in[2];
    const float* W1   = (const float*)d_in[3];
    const float* W2   = (const float*)d_in[4];
    float* out = (float*)d_out;

    const int B = in_sizes[0] / 51;
    const int blocks = (B + 255) / 256;
    hipLaunchKernelGGL(projts_kernel, dim3(blocks), dim3(256), 0, stream,
                       pred, gt, anc, W1, W2, out, B);
}